// Round 16
// baseline (94.415 us; speedup 1.0000x reference)
//
#include <hip/hip_runtime.h>

#define D 64
#define NCHUNK 256          // partition chunks (= blocks in k_part)
#define BSHIFT 7            // 128 nodes per bucket
#define BNODES 128
#define MAXBUK 1024         // static LDS; nBuckets = 782 for N=100k
#define CAPB 1792           // fixed edata capacity per bucket (mean 1536, +6.5 sigma)

// ---------------------------------------------------------------------------
// Pipeline (R15 post-mortem: agg became VALU-issue-bound — unconditional
// 4-wide ACC on zero registers + a 24-instr reduce tree per node. This round:
// 32-lane edge groups, dword loads (2ch/lane), degree-proportional unpack,
// 1-round reduce (2 shfl_xor), packed dword store. ~2x VALU cut, same bytes.)
//   1 k_prep  feat->bf16, W->bf16, init gcur
//   2 k_part  LDS count -> reserve ranges -> scatter records
//   3 k_fill3 per-bucket deg+scan+fill -> rowdeg(int2), eidx (byte offsets)
//   4 k_agg32 grid-stride gather, 32-lane groups -> bf16 mean
//   5 k_mfma  out = [feat|h]@[Ws|Wn]^T + b   (out written once)
// ---------------------------------------------------------------------------

typedef __attribute__((ext_vector_type(8))) short bf16x8;
typedef __attribute__((ext_vector_type(4))) float f32x4;

static __device__ __forceinline__ unsigned f2bf(float f)   // RNE bf16
{
    unsigned u = __float_as_uint(f);
    unsigned r = 0x7fffu + ((u >> 16) & 1u);
    return (u + r) >> 16;
}

static __device__ __forceinline__ void cvt8(const float* __restrict__ s,
                                            unsigned short* __restrict__ d)
{
    const float4 a = *(const float4*)s;
    const float4 b = *(const float4*)(s + 4);
    uint4 p;
    p.x = f2bf(a.x) | (f2bf(a.y) << 16);
    p.y = f2bf(a.z) | (f2bf(a.w) << 16);
    p.z = f2bf(b.x) | (f2bf(b.y) << 16);
    p.w = f2bf(b.z) | (f2bf(b.w) << 16);
    *(uint4*)d = p;
}

// feat->bf16 (grid-stride), W->bf16 (block 1), gcur init (block 0)
__global__ __launch_bounds__(256) void k_prep(
    const float* __restrict__ feat, unsigned short* __restrict__ featbf,
    const float* __restrict__ Ws, const float* __restrict__ Wn,
    unsigned short* __restrict__ wsbf, unsigned short* __restrict__ wnbf,
    int* __restrict__ gcur, int n8, int nBuckets)
{
    const int t = threadIdx.x;
    if (blockIdx.x == 0)
        for (int i = t; i < nBuckets; i += 256) gcur[i] = i * CAPB;
    if (blockIdx.x == 1)
        for (int i = t; i < (D * D) / 8; i += 256) {     // 512 groups of 8
            cvt8(Ws + i * 8, wsbf + i * 8);
            cvt8(Wn + i * 8, wnbf + i * 8);
        }
    for (int i = blockIdx.x * 256 + t; i < n8; i += gridDim.x * 256)
        cvt8(feat + (size_t)i * 8, featbf + (size_t)i * 8);
}

// count chunk per bucket (LDS) -> reserve global ranges -> scatter records
__global__ __launch_bounds__(256) void k_part(
    const int* __restrict__ src, const int* __restrict__ dst,
    int* __restrict__ gcur, int* __restrict__ edata,
    int nEdges, int nBuckets, int chunk)
{
    __shared__ int cnt[MAXBUK];
    __shared__ int cur[MAXBUK];
    const int t = threadIdx.x;
    for (int i = t; i < nBuckets; i += 256) cnt[i] = 0;
    __syncthreads();
    const int beg = blockIdx.x * chunk;
    const int end = min(beg + chunk, nEdges);
    for (int i = beg + t; i < end; i += 256)
        atomicAdd(&cnt[dst[i] >> BSHIFT], 1);            // LDS atomic
    __syncthreads();
    for (int i = t; i < nBuckets; i += 256) {
        const int c = cnt[i];
        if (c) cur[i] = atomicAdd(&gcur[i], c);          // reserve range
    }
    __syncthreads();
    for (int i = beg + t; i < end; i += 256) {           // dst re-read: L1-hot
        const int dv = dst[i];
        const int b  = dv >> BSHIFT;
        const int p  = atomicAdd(&cur[b], 1);            // LDS atomic
        edata[p] = src[i] | ((dv & (BNODES - 1)) << 20);
    }
}

// per-bucket fused deg + 128-wide LDS scan + CSR fill.
// bucket region = [b*CAPB, gcur[b]); writes rowdeg = {start, deg} per node;
// eidx entries are BYTE offsets into featbf (src * D * 2B = src<<7).
__global__ __launch_bounds__(256) void k_fill3(
    const int* __restrict__ edata, const int* __restrict__ gcur,
    int2* __restrict__ rowdeg, int* __restrict__ eidx, int nNodes)
{
    __shared__ int cnt[BNODES], pos[BNODES], cur[BNODES];
    const int b = blockIdx.x, t = threadIdx.x;
    const int beg = b * CAPB;
    const int end = gcur[b];                             // final fill level

    if (t < BNODES) cnt[t] = 0;
    __syncthreads();
    for (int i = beg + t; i < end; i += 256)
        atomicAdd(&cnt[edata[i] >> 20], 1);              // LDS atomic
    __syncthreads();
    if (t < BNODES) pos[t] = cnt[t];
    __syncthreads();
    for (int off = 1; off < BNODES; off <<= 1) {
        const int u = (t < BNODES && t >= off) ? pos[t - off] : 0;
        __syncthreads();
        if (t < BNODES) pos[t] += u;
        __syncthreads();
    }
    if (t < BNODES) {
        pos[t] -= cnt[t];                                // exclusive
        cur[t]  = beg + pos[t];
        const int node = b * BNODES + t;
        if (node < nNodes) rowdeg[node] = make_int2(beg + pos[t], cnt[t]);
    }
    __syncthreads();
    for (int i = beg + t; i < end; i += 256) {
        const int e = edata[i];
        const int p = atomicAdd(&cur[e >> 20], 1);       // LDS atomic
        eidx[p] = (e & 0xFFFFF) << 7;                    // byte offset
    }
}

// grid-stride gather: one wave per node, TWO 32-lane edge groups.
// Each lane owns 2 channels (one dword of the row); per 4 edges: 2 bpermute
// + 2 masked dword loads + 8 VALU. Reduce = 1 shfl_xor round. Packed store.
__global__ __launch_bounds__(256) void k_agg32(
    const unsigned short* __restrict__ featbf,
    const int2* __restrict__ rowdeg,
    const int* __restrict__ eidx,                        // byte offsets
    unsigned short* __restrict__ hmeanbf, int nNodes)
{
    const int lane = threadIdx.x & 63;
    const int half = lane >> 5;          // edge subgroup 0/1
    const int ch   = lane & 31;          // dword index within row (2 ch)
    const char* bp = (const char*)featbf + ch * 4;
    const int wid  = (blockIdx.x * blockDim.x + threadIdx.x) >> 6;
    const int nW   = (gridDim.x * blockDim.x) >> 6;

    for (int n = wid; n < nNodes; n += nW) {
        const int2 rd = rowdeg[n];                       // one 8B load
        const int beg = rd.x, m0 = rd.y;
        float a0 = 0.f, a1 = 0.f;
        for (int bb = 0; bb < m0; bb += 64) {
            const int m  = min(64, m0 - bb);
            const int sv = (lane < m) ? eidx[beg + bb + lane] : 0;  // coalesced
            for (int j = 0; j < m; j += 4) {             // wave-uniform count
                const int o0 = __shfl(sv, j + half, 64);
                const int o1 = __shfl(sv, j + 2 + half, 64);
                unsigned v0 = 0u, v1 = 0u;
                if (j + half < m)     v0 = *(const unsigned*)(bp + o0);
                if (j + 2 + half < m) v1 = *(const unsigned*)(bp + o1);
                a0 += __uint_as_float(v0 << 16);
                a1 += __uint_as_float(v0 & 0xffff0000u);
                a0 += __uint_as_float(v1 << 16);
                a1 += __uint_as_float(v1 & 0xffff0000u);
            }
        }
        a0 += __shfl_xor(a0, 32, 64);                    // combine halves
        a1 += __shfl_xor(a1, 32, 64);
        if (half == 0) {                                 // lanes 0..31
            const float inv = 1.f / fmaxf((float)m0, 1.f);
            const unsigned p = f2bf(a0 * inv) | (f2bf(a1 * inv) << 16);
            *(unsigned*)((char*)hmeanbf + (size_t)n * (D * 2) + ch * 4) = p;
        }
    }
}

// ---------------------------------------------------------------------------
// transform MFMA: out = [feat | h] (bf16) @ [Ws | Wn]^T (bf16) + b, f32 acc.
// All stage reads are straight bf16 copies; out is write-only.
// ---------------------------------------------------------------------------
__global__ __launch_bounds__(256) void k_transform_mfma(
    const unsigned short* __restrict__ featbf,
    const unsigned short* __restrict__ hmeanbf,
    const unsigned short* __restrict__ wsbf,
    const unsigned short* __restrict__ wnbf,
    const float* __restrict__ bias,
    float* __restrict__ out, int nNodes)
{
    __shared__ short Atile[64][136];   // +8 bf16 pad: row stride 68 dwords
    __shared__ short Btile[64][136];

    const int t    = threadIdx.x;
    const int base = blockIdx.x * 64;

    {
        const int r = t >> 2, c = t & 3;
        const int node = base + r;
        uint4* dA = (uint4*)&Atile[r][c * 32];
        uint4* dB = (uint4*)&Btile[r][c * 32];
        const uint4* sB = (const uint4*)((c < 2) ? &wsbf[r * D + c * 32]
                                                 : &wnbf[r * D + (c - 2) * 32]);
#pragma unroll
        for (int it = 0; it < 4; ++it) dB[it] = sB[it];

        if (node < nNodes) {
            const uint4* sA = (const uint4*)((c < 2)
                ? featbf  + (size_t)node * D + c * 32
                : hmeanbf + (size_t)node * D + (c - 2) * 32);
#pragma unroll
            for (int it = 0; it < 4; ++it) dA[it] = sA[it];
        } else {
            uint4 z = {0u, 0u, 0u, 0u};
#pragma unroll
            for (int it = 0; it < 4; ++it) dA[it] = z;
        }
    }
    __syncthreads();

    const int w  = t >> 6, l = t & 63;
    const int lr = l & 15, lk = l >> 4;

    f32x4 acc[4];
#pragma unroll
    for (int cf = 0; cf < 4; ++cf) {
        const float bv = bias[cf * 16 + lr];
        acc[cf] = (f32x4){bv, bv, bv, bv};
    }
#pragma unroll
    for (int ks = 0; ks < 4; ++ks) {
        const bf16x8 av = *(const bf16x8*)&Atile[w * 16 + lr][ks * 32 + lk * 8];
#pragma unroll
        for (int cf = 0; cf < 4; ++cf) {
            const bf16x8 bv = *(const bf16x8*)&Btile[cf * 16 + lr][ks * 32 + lk * 8];
            acc[cf] = __builtin_amdgcn_mfma_f32_16x16x32_bf16(av, bv, acc[cf],
                                                              0, 0, 0);
        }
    }
#pragma unroll
    for (int cf = 0; cf < 4; ++cf) {
#pragma unroll
        for (int j = 0; j < 4; ++j) {
            const int node = base + w * 16 + lk * 4 + j;
            if (node < nNodes)
                out[(size_t)node * D + cf * 16 + lr] = acc[cf][j];
        }
    }
}

// ---------------------------------------------------------------------------
extern "C" void kernel_launch(void* const* d_in, const int* in_sizes, int n_in,
                              void* d_out, int out_size, void* d_ws, size_t ws_size,
                              hipStream_t stream)
{
    const float* feat = (const float*)d_in[0];
    const int*   src  = (const int*)  d_in[1];
    const int*   dst  = (const int*)  d_in[2];
    const float* Ws   = (const float*)d_in[3];
    const float* Wn   = (const float*)d_in[4];
    const float* bias = (const float*)d_in[5];
    float*       out  = (float*)d_out;

    const int nEdges   = in_sizes[1];
    const int nNodes   = in_sizes[0] / D;                    // 100000
    const int nBuckets = (nNodes + BNODES - 1) >> BSHIFT;    // 782
    const int chunk    = (nEdges + NCHUNK - 1) / NCHUNK;     // 4688
    const int nBT      = (nNodes + 63) / 64;                 // 1563

    // ws: gcur[1024] | rowdeg int2[N] | edata[782*CAPB] | eidx[782*CAPB]
    //     | wsbf,wnbf | featbf | hmeanbf   ~37.7 MB (ws is 256 MB)
    int*  gcur   = (int*)d_ws;
    int2* rowdeg = (int2*)(gcur + 1024);
    int*  edata  = (int*)(rowdeg + nNodes);
    int*  eidx   = edata + nBuckets * CAPB;
    unsigned short* wsbf    = (unsigned short*)(eidx + nBuckets * CAPB);
    unsigned short* wnbf    = wsbf + D * D;
    unsigned short* featbf  = wnbf + D * D;
    unsigned short* hmeanbf = featbf + (size_t)nNodes * D;

    k_prep <<<1024, 256, 0, stream>>>(feat, featbf, Ws, Wn, wsbf, wnbf,
                                      gcur, nNodes * D / 8, nBuckets);
    k_part <<<NCHUNK, 256, 0, stream>>>(src, dst, gcur, edata,
                                        nEdges, nBuckets, chunk);
    k_fill3<<<nBuckets, 256, 0, stream>>>(edata, gcur, rowdeg, eidx, nNodes);
    k_agg32<<<4096, 256, 0, stream>>>(featbf, rowdeg, eidx, hmeanbf, nNodes);
    k_transform_mfma<<<nBT, 256, 0, stream>>>(featbf, hmeanbf, wsbf, wnbf,
                                              bias, out, nNodes);
}

// Round 17
// 86.124 us; speedup vs baseline: 1.0963x; 1.0963x over previous
//
#include <hip/hip_runtime.h>

#define D 64
#define NCHUNK 256          // partition chunks (= blocks in k_part)
#define BSHIFT 7            // 128 nodes per bucket
#define BNODES 128
#define MAXBUK 1024         // static LDS; nBuckets = 782 for N=100k
#define CAPB 1792           // fixed edata capacity per bucket (mean 1536, +6.5 sigma)

// ---------------------------------------------------------------------------
// Pipeline (R16 post-mortem: halving agg VALU changed nothing -> gather is
// load-LATENCY-bound with only ~2 loads in flight (runtime-bound j-loop, no
// compiler unroll). This round: 8-deep static load batching per j-iter at the
// 32-lane-group shape (R14's depth without its 8-lane-group VALU waste).)
//   1 k_prep  feat->bf16, W->bf16, init gcur
//   2 k_part  LDS count -> reserve ranges -> scatter records
//   3 k_fill3 per-bucket deg+scan+fill -> rowdeg(int2), eidx (byte offsets)
//   4 k_agg32 grid-stride gather, 8-deep load pipeline -> bf16 mean
//   5 k_mfma  out = [feat|h]@[Ws|Wn]^T + b   (out written once)
// ---------------------------------------------------------------------------

typedef __attribute__((ext_vector_type(8))) short bf16x8;
typedef __attribute__((ext_vector_type(4))) float f32x4;

static __device__ __forceinline__ unsigned f2bf(float f)   // RNE bf16
{
    unsigned u = __float_as_uint(f);
    unsigned r = 0x7fffu + ((u >> 16) & 1u);
    return (u + r) >> 16;
}

static __device__ __forceinline__ void cvt8(const float* __restrict__ s,
                                            unsigned short* __restrict__ d)
{
    const float4 a = *(const float4*)s;
    const float4 b = *(const float4*)(s + 4);
    uint4 p;
    p.x = f2bf(a.x) | (f2bf(a.y) << 16);
    p.y = f2bf(a.z) | (f2bf(a.w) << 16);
    p.z = f2bf(b.x) | (f2bf(b.y) << 16);
    p.w = f2bf(b.z) | (f2bf(b.w) << 16);
    *(uint4*)d = p;
}

// feat->bf16 (grid-stride), W->bf16 (block 1), gcur init (block 0)
__global__ __launch_bounds__(256) void k_prep(
    const float* __restrict__ feat, unsigned short* __restrict__ featbf,
    const float* __restrict__ Ws, const float* __restrict__ Wn,
    unsigned short* __restrict__ wsbf, unsigned short* __restrict__ wnbf,
    int* __restrict__ gcur, int n8, int nBuckets)
{
    const int t = threadIdx.x;
    if (blockIdx.x == 0)
        for (int i = t; i < nBuckets; i += 256) gcur[i] = i * CAPB;
    if (blockIdx.x == 1)
        for (int i = t; i < (D * D) / 8; i += 256) {     // 512 groups of 8
            cvt8(Ws + i * 8, wsbf + i * 8);
            cvt8(Wn + i * 8, wnbf + i * 8);
        }
    for (int i = blockIdx.x * 256 + t; i < n8; i += gridDim.x * 256)
        cvt8(feat + (size_t)i * 8, featbf + (size_t)i * 8);
}

// count chunk per bucket (LDS) -> reserve global ranges -> scatter records
__global__ __launch_bounds__(256) void k_part(
    const int* __restrict__ src, const int* __restrict__ dst,
    int* __restrict__ gcur, int* __restrict__ edata,
    int nEdges, int nBuckets, int chunk)
{
    __shared__ int cnt[MAXBUK];
    __shared__ int cur[MAXBUK];
    const int t = threadIdx.x;
    for (int i = t; i < nBuckets; i += 256) cnt[i] = 0;
    __syncthreads();
    const int beg = blockIdx.x * chunk;
    const int end = min(beg + chunk, nEdges);
    for (int i = beg + t; i < end; i += 256)
        atomicAdd(&cnt[dst[i] >> BSHIFT], 1);            // LDS atomic
    __syncthreads();
    for (int i = t; i < nBuckets; i += 256) {
        const int c = cnt[i];
        if (c) cur[i] = atomicAdd(&gcur[i], c);          // reserve range
    }
    __syncthreads();
    for (int i = beg + t; i < end; i += 256) {           // dst re-read: L1-hot
        const int dv = dst[i];
        const int b  = dv >> BSHIFT;
        const int p  = atomicAdd(&cur[b], 1);            // LDS atomic
        edata[p] = src[i] | ((dv & (BNODES - 1)) << 20);
    }
}

// per-bucket fused deg + 128-wide LDS scan + CSR fill.
// bucket region = [b*CAPB, gcur[b]); writes rowdeg = {start, deg} per node;
// eidx entries are BYTE offsets into featbf (src * D * 2B = src<<7).
__global__ __launch_bounds__(256) void k_fill3(
    const int* __restrict__ edata, const int* __restrict__ gcur,
    int2* __restrict__ rowdeg, int* __restrict__ eidx, int nNodes)
{
    __shared__ int cnt[BNODES], pos[BNODES], cur[BNODES];
    const int b = blockIdx.x, t = threadIdx.x;
    const int beg = b * CAPB;
    const int end = gcur[b];                             // final fill level

    if (t < BNODES) cnt[t] = 0;
    __syncthreads();
    for (int i = beg + t; i < end; i += 256)
        atomicAdd(&cnt[edata[i] >> 20], 1);              // LDS atomic
    __syncthreads();
    if (t < BNODES) pos[t] = cnt[t];
    __syncthreads();
    for (int off = 1; off < BNODES; off <<= 1) {
        const int u = (t < BNODES && t >= off) ? pos[t - off] : 0;
        __syncthreads();
        if (t < BNODES) pos[t] += u;
        __syncthreads();
    }
    if (t < BNODES) {
        pos[t] -= cnt[t];                                // exclusive
        cur[t]  = beg + pos[t];
        const int node = b * BNODES + t;
        if (node < nNodes) rowdeg[node] = make_int2(beg + pos[t], cnt[t]);
    }
    __syncthreads();
    for (int i = beg + t; i < end; i += 256) {
        const int e = edata[i];
        const int p = atomicAdd(&cur[e >> 20], 1);       // LDS atomic
        eidx[p] = (e & 0xFFFFF) << 7;                    // byte offset
    }
}

// grid-stride gather: one wave per node, TWO 32-lane edge groups, 8-deep
// static load batching per iteration (16 edges). All 8 shfls + 8 masked
// loads issue before any consume -> 8 loads in flight per wave.
__global__ __launch_bounds__(256) void k_agg32(
    const unsigned short* __restrict__ featbf,
    const int2* __restrict__ rowdeg,
    const int* __restrict__ eidx,                        // byte offsets
    unsigned short* __restrict__ hmeanbf, int nNodes)
{
    const int lane = threadIdx.x & 63;
    const int half = lane >> 5;          // edge subgroup 0/1
    const int ch   = lane & 31;          // dword index within row (2 ch)
    const char* bp = (const char*)featbf + ch * 4;
    const int wid  = (blockIdx.x * blockDim.x + threadIdx.x) >> 6;
    const int nW   = (gridDim.x * blockDim.x) >> 6;

    for (int n = wid; n < nNodes; n += nW) {
        const int2 rd = rowdeg[n];                       // one 8B load
        const int beg = rd.x, m0 = rd.y;
        float a0 = 0.f, a1 = 0.f;
        for (int bb = 0; bb < m0; bb += 64) {
            const int m  = min(64, m0 - bb);
            const int sv = (lane < m) ? eidx[beg + bb + lane] : 0;  // coalesced
            for (int j = 0; j < m; j += 16) {            // 16 edges / iter
                int      o0, o1, o2, o3, o4, o5, o6, o7;
                unsigned v0 = 0u, v1 = 0u, v2 = 0u, v3 = 0u;
                unsigned v4 = 0u, v5 = 0u, v6 = 0u, v7 = 0u;
                // phase 1: all address shfls (edge j+2q+half, q=0..7; <=63)
                o0 = __shfl(sv, j +  0 + half, 64);
                o1 = __shfl(sv, j +  2 + half, 64);
                o2 = __shfl(sv, j +  4 + half, 64);
                o3 = __shfl(sv, j +  6 + half, 64);
                o4 = __shfl(sv, j +  8 + half, 64);
                o5 = __shfl(sv, j + 10 + half, 64);
                o6 = __shfl(sv, j + 12 + half, 64);
                o7 = __shfl(sv, j + 14 + half, 64);
                // phase 2: issue all masked loads back-to-back (8 in flight)
                if (j +  0 + half < m) v0 = *(const unsigned*)(bp + o0);
                if (j +  2 + half < m) v1 = *(const unsigned*)(bp + o1);
                if (j +  4 + half < m) v2 = *(const unsigned*)(bp + o2);
                if (j +  6 + half < m) v3 = *(const unsigned*)(bp + o3);
                if (j +  8 + half < m) v4 = *(const unsigned*)(bp + o4);
                if (j + 10 + half < m) v5 = *(const unsigned*)(bp + o5);
                if (j + 12 + half < m) v6 = *(const unsigned*)(bp + o6);
                if (j + 14 + half < m) v7 = *(const unsigned*)(bp + o7);
                // phase 3: consume
#define ACC(v) a0 += __uint_as_float((v) << 16);                    \
               a1 += __uint_as_float((v) & 0xffff0000u);
                ACC(v0) ACC(v1) ACC(v2) ACC(v3)
                ACC(v4) ACC(v5) ACC(v6) ACC(v7)
#undef ACC
            }
        }
        a0 += __shfl_xor(a0, 32, 64);                    // combine halves
        a1 += __shfl_xor(a1, 32, 64);
        if (half == 0) {                                 // lanes 0..31
            const float inv = 1.f / fmaxf((float)m0, 1.f);
            const unsigned p = f2bf(a0 * inv) | (f2bf(a1 * inv) << 16);
            *(unsigned*)((char*)hmeanbf + (size_t)n * (D * 2) + ch * 4) = p;
        }
    }
}

// ---------------------------------------------------------------------------
// transform MFMA: out = [feat | h] (bf16) @ [Ws | Wn]^T (bf16) + b, f32 acc.
// All stage reads are straight bf16 copies; out is write-only.
// ---------------------------------------------------------------------------
__global__ __launch_bounds__(256) void k_transform_mfma(
    const unsigned short* __restrict__ featbf,
    const unsigned short* __restrict__ hmeanbf,
    const unsigned short* __restrict__ wsbf,
    const unsigned short* __restrict__ wnbf,
    const float* __restrict__ bias,
    float* __restrict__ out, int nNodes)
{
    __shared__ short Atile[64][136];   // +8 bf16 pad: row stride 68 dwords
    __shared__ short Btile[64][136];

    const int t    = threadIdx.x;
    const int base = blockIdx.x * 64;

    {
        const int r = t >> 2, c = t & 3;
        const int node = base + r;
        uint4* dA = (uint4*)&Atile[r][c * 32];
        uint4* dB = (uint4*)&Btile[r][c * 32];
        const uint4* sB = (const uint4*)((c < 2) ? &wsbf[r * D + c * 32]
                                                 : &wnbf[r * D + (c - 2) * 32]);
#pragma unroll
        for (int it = 0; it < 4; ++it) dB[it] = sB[it];

        if (node < nNodes) {
            const uint4* sA = (const uint4*)((c < 2)
                ? featbf  + (size_t)node * D + c * 32
                : hmeanbf + (size_t)node * D + (c - 2) * 32);
#pragma unroll
            for (int it = 0; it < 4; ++it) dA[it] = sA[it];
        } else {
            uint4 z = {0u, 0u, 0u, 0u};
#pragma unroll
            for (int it = 0; it < 4; ++it) dA[it] = z;
        }
    }
    __syncthreads();

    const int w  = t >> 6, l = t & 63;
    const int lr = l & 15, lk = l >> 4;

    f32x4 acc[4];
#pragma unroll
    for (int cf = 0; cf < 4; ++cf) {
        const float bv = bias[cf * 16 + lr];
        acc[cf] = (f32x4){bv, bv, bv, bv};
    }
#pragma unroll
    for (int ks = 0; ks < 4; ++ks) {
        const bf16x8 av = *(const bf16x8*)&Atile[w * 16 + lr][ks * 32 + lk * 8];
#pragma unroll
        for (int cf = 0; cf < 4; ++cf) {
            const bf16x8 bv = *(const bf16x8*)&Btile[cf * 16 + lr][ks * 32 + lk * 8];
            acc[cf] = __builtin_amdgcn_mfma_f32_16x16x32_bf16(av, bv, acc[cf],
                                                              0, 0, 0);
        }
    }
#pragma unroll
    for (int cf = 0; cf < 4; ++cf) {
#pragma unroll
        for (int j = 0; j < 4; ++j) {
            const int node = base + w * 16 + lk * 4 + j;
            if (node < nNodes)
                out[(size_t)node * D + cf * 16 + lr] = acc[cf][j];
        }
    }
}

// ---------------------------------------------------------------------------
extern "C" void kernel_launch(void* const* d_in, const int* in_sizes, int n_in,
                              void* d_out, int out_size, void* d_ws, size_t ws_size,
                              hipStream_t stream)
{
    const float* feat = (const float*)d_in[0];
    const int*   src  = (const int*)  d_in[1];
    const int*   dst  = (const int*)  d_in[2];
    const float* Ws   = (const float*)d_in[3];
    const float* Wn   = (const float*)d_in[4];
    const float* bias = (const float*)d_in[5];
    float*       out  = (float*)d_out;

    const int nEdges   = in_sizes[1];
    const int nNodes   = in_sizes[0] / D;                    // 100000
    const int nBuckets = (nNodes + BNODES - 1) >> BSHIFT;    // 782
    const int chunk    = (nEdges + NCHUNK - 1) / NCHUNK;     // 4688
    const int nBT      = (nNodes + 63) / 64;                 // 1563

    // ws: gcur[1024] | rowdeg int2[N] | edata[782*CAPB] | eidx[782*CAPB]
    //     | wsbf,wnbf | featbf | hmeanbf   ~37.7 MB (ws is 256 MB)
    int*  gcur   = (int*)d_ws;
    int2* rowdeg = (int2*)(gcur + 1024);
    int*  edata  = (int*)(rowdeg + nNodes);
    int*  eidx   = edata + nBuckets * CAPB;
    unsigned short* wsbf    = (unsigned short*)(eidx + nBuckets * CAPB);
    unsigned short* wnbf    = wsbf + D * D;
    unsigned short* featbf  = wnbf + D * D;
    unsigned short* hmeanbf = featbf + (size_t)nNodes * D;

    k_prep <<<1024, 256, 0, stream>>>(feat, featbf, Ws, Wn, wsbf, wnbf,
                                      gcur, nNodes * D / 8, nBuckets);
    k_part <<<NCHUNK, 256, 0, stream>>>(src, dst, gcur, edata,
                                        nEdges, nBuckets, chunk);
    k_fill3<<<nBuckets, 256, 0, stream>>>(edata, gcur, rowdeg, eidx, nNodes);
    k_agg32<<<4096, 256, 0, stream>>>(featbf, rowdeg, eidx, hmeanbf, nNodes);
    k_transform_mfma<<<nBT, 256, 0, stream>>>(featbf, hmeanbf, wsbf, wnbf,
                                              bias, out, nNodes);
}

// Round 18
// 84.388 us; speedup vs baseline: 1.1188x; 1.0206x over previous
//
#include <hip/hip_runtime.h>

#define D 64
#define NCHUNK 256          // partition chunks (= blocks in k_part)
#define BSHIFT 7            // 128 nodes per bucket
#define BNODES 128
#define MAXBUK 1024         // static LDS; nBuckets = 782 for N=100k
#define CAPB 1792           // fixed edata capacity per bucket (mean 1536, +6.5 sigma)

// ---------------------------------------------------------------------------
// Pipeline (R17 post-mortem: load-depth batching bought 8.6%; agg still pays
// 3 chained memory latencies per node (rowdeg -> eidx -> feat). This round:
// software-pipeline across node iterations — prefetch next node's rowdeg at
// iter start and its eidx right after this node's feat loads issue. Steady
// state = one latency per node.)
//   1 k_prep  feat->bf16, W->bf16, init gcur
//   2 k_part  LDS count -> reserve ranges -> scatter records
//   3 k_fill3 per-bucket deg+scan+fill -> rowdeg(int2), eidx (byte offsets)
//   4 k_agg32 node-pipelined gather -> bf16 mean
//   5 k_mfma  out = [feat|h]@[Ws|Wn]^T + b   (out written once)
// ---------------------------------------------------------------------------

typedef __attribute__((ext_vector_type(8))) short bf16x8;
typedef __attribute__((ext_vector_type(4))) float f32x4;

static __device__ __forceinline__ unsigned f2bf(float f)   // RNE bf16
{
    unsigned u = __float_as_uint(f);
    unsigned r = 0x7fffu + ((u >> 16) & 1u);
    return (u + r) >> 16;
}

static __device__ __forceinline__ void cvt8(const float* __restrict__ s,
                                            unsigned short* __restrict__ d)
{
    const float4 a = *(const float4*)s;
    const float4 b = *(const float4*)(s + 4);
    uint4 p;
    p.x = f2bf(a.x) | (f2bf(a.y) << 16);
    p.y = f2bf(a.z) | (f2bf(a.w) << 16);
    p.z = f2bf(b.x) | (f2bf(b.y) << 16);
    p.w = f2bf(b.z) | (f2bf(b.w) << 16);
    *(uint4*)d = p;
}

// feat->bf16 (grid-stride), W->bf16 (block 1), gcur init (block 0)
__global__ __launch_bounds__(256) void k_prep(
    const float* __restrict__ feat, unsigned short* __restrict__ featbf,
    const float* __restrict__ Ws, const float* __restrict__ Wn,
    unsigned short* __restrict__ wsbf, unsigned short* __restrict__ wnbf,
    int* __restrict__ gcur, int n8, int nBuckets)
{
    const int t = threadIdx.x;
    if (blockIdx.x == 0)
        for (int i = t; i < nBuckets; i += 256) gcur[i] = i * CAPB;
    if (blockIdx.x == 1)
        for (int i = t; i < (D * D) / 8; i += 256) {     // 512 groups of 8
            cvt8(Ws + i * 8, wsbf + i * 8);
            cvt8(Wn + i * 8, wnbf + i * 8);
        }
    for (int i = blockIdx.x * 256 + t; i < n8; i += gridDim.x * 256)
        cvt8(feat + (size_t)i * 8, featbf + (size_t)i * 8);
}

// count chunk per bucket (LDS) -> reserve global ranges -> scatter records
__global__ __launch_bounds__(256) void k_part(
    const int* __restrict__ src, const int* __restrict__ dst,
    int* __restrict__ gcur, int* __restrict__ edata,
    int nEdges, int nBuckets, int chunk)
{
    __shared__ int cnt[MAXBUK];
    __shared__ int cur[MAXBUK];
    const int t = threadIdx.x;
    for (int i = t; i < nBuckets; i += 256) cnt[i] = 0;
    __syncthreads();
    const int beg = blockIdx.x * chunk;
    const int end = min(beg + chunk, nEdges);
    for (int i = beg + t; i < end; i += 256)
        atomicAdd(&cnt[dst[i] >> BSHIFT], 1);            // LDS atomic
    __syncthreads();
    for (int i = t; i < nBuckets; i += 256) {
        const int c = cnt[i];
        if (c) cur[i] = atomicAdd(&gcur[i], c);          // reserve range
    }
    __syncthreads();
    for (int i = beg + t; i < end; i += 256) {           // dst re-read: L1-hot
        const int dv = dst[i];
        const int b  = dv >> BSHIFT;
        const int p  = atomicAdd(&cur[b], 1);            // LDS atomic
        edata[p] = src[i] | ((dv & (BNODES - 1)) << 20);
    }
}

// per-bucket fused deg + 128-wide LDS scan + CSR fill.
// bucket region = [b*CAPB, gcur[b]); writes rowdeg = {start, deg} per node;
// eidx entries are BYTE offsets into featbf (src * D * 2B = src<<7).
__global__ __launch_bounds__(256) void k_fill3(
    const int* __restrict__ edata, const int* __restrict__ gcur,
    int2* __restrict__ rowdeg, int* __restrict__ eidx, int nNodes)
{
    __shared__ int cnt[BNODES], pos[BNODES], cur[BNODES];
    const int b = blockIdx.x, t = threadIdx.x;
    const int beg = b * CAPB;
    const int end = gcur[b];                             // final fill level

    if (t < BNODES) cnt[t] = 0;
    __syncthreads();
    for (int i = beg + t; i < end; i += 256)
        atomicAdd(&cnt[edata[i] >> 20], 1);              // LDS atomic
    __syncthreads();
    if (t < BNODES) pos[t] = cnt[t];
    __syncthreads();
    for (int off = 1; off < BNODES; off <<= 1) {
        const int u = (t < BNODES && t >= off) ? pos[t - off] : 0;
        __syncthreads();
        if (t < BNODES) pos[t] += u;
        __syncthreads();
    }
    if (t < BNODES) {
        pos[t] -= cnt[t];                                // exclusive
        cur[t]  = beg + pos[t];
        const int node = b * BNODES + t;
        if (node < nNodes) rowdeg[node] = make_int2(beg + pos[t], cnt[t]);
    }
    __syncthreads();
    for (int i = beg + t; i < end; i += 256) {
        const int e = edata[i];
        const int p = atomicAdd(&cur[e >> 20], 1);       // LDS atomic
        eidx[p] = (e & 0xFFFFF) << 7;                    // byte offset
    }
}

// node-pipelined gather: one wave per node, TWO 32-lane edge groups, 8-deep
// load batches. Next node's rowdeg prefetched at iter start; next node's
// eidx issued right after this node's feat loads (latency hides under them).
__global__ __launch_bounds__(256) void k_agg32(
    const unsigned short* __restrict__ featbf,
    const int2* __restrict__ rowdeg,
    const int* __restrict__ eidx,                        // byte offsets
    unsigned short* __restrict__ hmeanbf, int nNodes)
{
    const int lane = threadIdx.x & 63;
    const int half = lane >> 5;          // edge subgroup 0/1
    const int ch   = lane & 31;          // dword index within row (2 ch)
    const char* bp = (const char*)featbf + ch * 4;
    const int wid  = (blockIdx.x * blockDim.x + threadIdx.x) >> 6;
    const int nW   = (gridDim.x * blockDim.x) >> 6;

    int n = wid;
    if (n >= nNodes) return;
    int2 rd = rowdeg[n];
    int sv = (lane < min(rd.y, 64)) ? eidx[rd.x + lane] : 0;

    while (true) {
        const int nn = n + nW;
        int2 rdN = make_int2(0, 0);
        if (nn < nNodes) rdN = rowdeg[nn];               // prefetch rowdeg

        const int m0 = rd.y;
        float a0 = 0.f, a1 = 0.f;
        int svN = 0;
        bool svNdone = false;

#define BATCH16(SVREG, JBASE, M)                                          \
        {                                                                 \
            int      o0, o1, o2, o3, o4, o5, o6, o7;                      \
            unsigned v0 = 0u, v1 = 0u, v2 = 0u, v3 = 0u;                  \
            unsigned v4 = 0u, v5 = 0u, v6 = 0u, v7 = 0u;                  \
            o0 = __shfl(SVREG, (JBASE) +  0 + half, 64);                  \
            o1 = __shfl(SVREG, (JBASE) +  2 + half, 64);                  \
            o2 = __shfl(SVREG, (JBASE) +  4 + half, 64);                  \
            o3 = __shfl(SVREG, (JBASE) +  6 + half, 64);                  \
            o4 = __shfl(SVREG, (JBASE) +  8 + half, 64);                  \
            o5 = __shfl(SVREG, (JBASE) + 10 + half, 64);                  \
            o6 = __shfl(SVREG, (JBASE) + 12 + half, 64);                  \
            o7 = __shfl(SVREG, (JBASE) + 14 + half, 64);                  \
            if ((JBASE) +  0 + half < (M)) v0 = *(const unsigned*)(bp + o0); \
            if ((JBASE) +  2 + half < (M)) v1 = *(const unsigned*)(bp + o1); \
            if ((JBASE) +  4 + half < (M)) v2 = *(const unsigned*)(bp + o2); \
            if ((JBASE) +  6 + half < (M)) v3 = *(const unsigned*)(bp + o3); \
            if ((JBASE) +  8 + half < (M)) v4 = *(const unsigned*)(bp + o4); \
            if ((JBASE) + 10 + half < (M)) v5 = *(const unsigned*)(bp + o5); \
            if ((JBASE) + 12 + half < (M)) v6 = *(const unsigned*)(bp + o6); \
            if ((JBASE) + 14 + half < (M)) v7 = *(const unsigned*)(bp + o7); \
            if (!svNdone) {   /* wave-uniform: prefetch next eidx now */   \
                svNdone = true;                                           \
                if (nn < nNodes && lane < min(rdN.y, 64))                 \
                    svN = eidx[rdN.x + lane];                             \
            }                                                             \
            a0 += __uint_as_float(v0 << 16);                              \
            a1 += __uint_as_float(v0 & 0xffff0000u);                      \
            a0 += __uint_as_float(v1 << 16);                              \
            a1 += __uint_as_float(v1 & 0xffff0000u);                      \
            a0 += __uint_as_float(v2 << 16);                              \
            a1 += __uint_as_float(v2 & 0xffff0000u);                      \
            a0 += __uint_as_float(v3 << 16);                              \
            a1 += __uint_as_float(v3 & 0xffff0000u);                      \
            a0 += __uint_as_float(v4 << 16);                              \
            a1 += __uint_as_float(v4 & 0xffff0000u);                      \
            a0 += __uint_as_float(v5 << 16);                              \
            a1 += __uint_as_float(v5 & 0xffff0000u);                      \
            a0 += __uint_as_float(v6 << 16);                              \
            a1 += __uint_as_float(v6 & 0xffff0000u);                      \
            a0 += __uint_as_float(v7 << 16);                              \
            a1 += __uint_as_float(v7 & 0xffff0000u);                      \
        }

        if (m0 <= 64) {                                  // fast path
            for (int j = 0; j < m0; j += 16)
                BATCH16(sv, j, m0)
        } else {                                         // rare: deg > 64
            for (int bb = 0; bb < m0; bb += 64) {
                const int m = min(64, m0 - bb);
                const int s2 = (lane < m) ? eidx[rd.x + bb + lane] : 0;
                for (int j = 0; j < m; j += 16)
                    BATCH16(s2, j, m)
            }
        }
        if (!svNdone && nn < nNodes && lane < min(rdN.y, 64))
            svN = eidx[rdN.x + lane];                    // deg==0 fallback
#undef BATCH16

        a0 += __shfl_xor(a0, 32, 64);                    // combine halves
        a1 += __shfl_xor(a1, 32, 64);
        if (half == 0) {                                 // lanes 0..31
            const float inv = 1.f / fmaxf((float)m0, 1.f);
            const unsigned p = f2bf(a0 * inv) | (f2bf(a1 * inv) << 16);
            *(unsigned*)((char*)hmeanbf + (size_t)n * (D * 2) + ch * 4) = p;
        }

        if (nn >= nNodes) break;
        n = nn; rd = rdN; sv = svN;
    }
}

// ---------------------------------------------------------------------------
// transform MFMA: out = [feat | h] (bf16) @ [Ws | Wn]^T (bf16) + b, f32 acc.
// All stage reads are straight bf16 copies; out is write-only.
// ---------------------------------------------------------------------------
__global__ __launch_bounds__(256) void k_transform_mfma(
    const unsigned short* __restrict__ featbf,
    const unsigned short* __restrict__ hmeanbf,
    const unsigned short* __restrict__ wsbf,
    const unsigned short* __restrict__ wnbf,
    const float* __restrict__ bias,
    float* __restrict__ out, int nNodes)
{
    __shared__ short Atile[64][136];   // +8 bf16 pad: row stride 68 dwords
    __shared__ short Btile[64][136];

    const int t    = threadIdx.x;
    const int base = blockIdx.x * 64;

    {
        const int r = t >> 2, c = t & 3;
        const int node = base + r;
        uint4* dA = (uint4*)&Atile[r][c * 32];
        uint4* dB = (uint4*)&Btile[r][c * 32];
        const uint4* sB = (const uint4*)((c < 2) ? &wsbf[r * D + c * 32]
                                                 : &wnbf[r * D + (c - 2) * 32]);
#pragma unroll
        for (int it = 0; it < 4; ++it) dB[it] = sB[it];

        if (node < nNodes) {
            const uint4* sA = (const uint4*)((c < 2)
                ? featbf  + (size_t)node * D + c * 32
                : hmeanbf + (size_t)node * D + (c - 2) * 32);
#pragma unroll
            for (int it = 0; it < 4; ++it) dA[it] = sA[it];
        } else {
            uint4 z = {0u, 0u, 0u, 0u};
#pragma unroll
            for (int it = 0; it < 4; ++it) dA[it] = z;
        }
    }
    __syncthreads();

    const int w  = t >> 6, l = t & 63;
    const int lr = l & 15, lk = l >> 4;

    f32x4 acc[4];
#pragma unroll
    for (int cf = 0; cf < 4; ++cf) {
        const float bv = bias[cf * 16 + lr];
        acc[cf] = (f32x4){bv, bv, bv, bv};
    }
#pragma unroll
    for (int ks = 0; ks < 4; ++ks) {
        const bf16x8 av = *(const bf16x8*)&Atile[w * 16 + lr][ks * 32 + lk * 8];
#pragma unroll
        for (int cf = 0; cf < 4; ++cf) {
            const bf16x8 bv = *(const bf16x8*)&Btile[cf * 16 + lr][ks * 32 + lk * 8];
            acc[cf] = __builtin_amdgcn_mfma_f32_16x16x32_bf16(av, bv, acc[cf],
                                                              0, 0, 0);
        }
    }
#pragma unroll
    for (int cf = 0; cf < 4; ++cf) {
#pragma unroll
        for (int j = 0; j < 4; ++j) {
            const int node = base + w * 16 + lk * 4 + j;
            if (node < nNodes)
                out[(size_t)node * D + cf * 16 + lr] = acc[cf][j];
        }
    }
}

// ---------------------------------------------------------------------------
extern "C" void kernel_launch(void* const* d_in, const int* in_sizes, int n_in,
                              void* d_out, int out_size, void* d_ws, size_t ws_size,
                              hipStream_t stream)
{
    const float* feat = (const float*)d_in[0];
    const int*   src  = (const int*)  d_in[1];
    const int*   dst  = (const int*)  d_in[2];
    const float* Ws   = (const float*)d_in[3];
    const float* Wn   = (const float*)d_in[4];
    const float* bias = (const float*)d_in[5];
    float*       out  = (float*)d_out;

    const int nEdges   = in_sizes[1];
    const int nNodes   = in_sizes[0] / D;                    // 100000
    const int nBuckets = (nNodes + BNODES - 1) >> BSHIFT;    // 782
    const int chunk    = (nEdges + NCHUNK - 1) / NCHUNK;     // 4688
    const int nBT      = (nNodes + 63) / 64;                 // 1563

    // ws: gcur[1024] | rowdeg int2[N] | edata[782*CAPB] | eidx[782*CAPB]
    //     | wsbf,wnbf | featbf | hmeanbf   ~37.7 MB (ws is 256 MB)
    int*  gcur   = (int*)d_ws;
    int2* rowdeg = (int2*)(gcur + 1024);
    int*  edata  = (int*)(rowdeg + nNodes);
    int*  eidx   = edata + nBuckets * CAPB;
    unsigned short* wsbf    = (unsigned short*)(eidx + nBuckets * CAPB);
    unsigned short* wnbf    = wsbf + D * D;
    unsigned short* featbf  = wnbf + D * D;
    unsigned short* hmeanbf = featbf + (size_t)nNodes * D;

    k_prep <<<1024, 256, 0, stream>>>(feat, featbf, Ws, Wn, wsbf, wnbf,
                                      gcur, nNodes * D / 8, nBuckets);
    k_part <<<NCHUNK, 256, 0, stream>>>(src, dst, gcur, edata,
                                        nEdges, nBuckets, chunk);
    k_fill3<<<nBuckets, 256, 0, stream>>>(edata, gcur, rowdeg, eidx, nNodes);
    k_agg32<<<4096, 256, 0, stream>>>(featbf, rowdeg, eidx, hmeanbf, nNodes);
    k_transform_mfma<<<nBT, 256, 0, stream>>>(featbf, hmeanbf, wsbf, wnbf,
                                              bias, out, nNodes);
}